// Round 23
// baseline (131.507 us; speedup 1.0000x reference)
//
#include <hip/hip_runtime.h>
#include <hip/hip_bf16.h>

#define NHEAD 12
#define TSEQ 2048
#define CEMB 768
#define DHEAD 64
#define NBATCH 4

typedef __attribute__((ext_vector_type(8))) short bf16x8;
typedef __attribute__((ext_vector_type(4))) float f32x4;
typedef __attribute__((ext_vector_type(4))) unsigned u32x4;

template <int N> struct IC { static constexpr int value = N; };

__device__ __forceinline__ ushort f2bf(float f) {
  union { float f; unsigned u; } v; v.f = f;
  unsigned u = v.u;
  u += 0x7FFFu + ((u >> 16) & 1u);   // RNE to bf16
  return (ushort)(u >> 16);
}

// packed f32x2 -> bf16x2 (1 inst, RNE) — T12 primitive
__device__ __forceinline__ unsigned cvt_pk_bf16(float lo, float hi) {
  unsigned r;
  asm("v_cvt_pk_bf16_f32 %0, %1, %2" : "=v"(r) : "v"(lo), "v"(hi));
  return r;
}

// raw v_exp_f32: D = 2^S0 (scores pre-scaled to log2 domain)
__device__ __forceinline__ float exp2_raw(float x) {
  float r;
  asm("v_exp_f32 %0, %1" : "=v"(r) : "v"(x));
  return r;
}

// v_permlane32_swap_b32 (semantics validated R14):
// new_a = [a.lanes0-31 | b.lanes0-31], new_b = [a.lanes32-63 | b.lanes32-63]
__device__ __forceinline__ void permswap32(unsigned& a, unsigned& b) {
  asm("v_permlane32_swap_b32 %0, %1" : "+v"(a), "+v"(b));
}
// v_permlane16_swap_b32 (validated R15): swap a's odd 16-rows with b's even 16-rows
__device__ __forceinline__ void permswap16(unsigned& a, unsigned& b) {
  asm("v_permlane16_swap_b32 %0, %1" : "+v"(a), "+v"(b));
}

// ---------- fused prep: cast x -> bf16, transpose+cast Wa and Wo ----------
__global__ __launch_bounds__(256)
void prep(const float* __restrict__ x, ushort* __restrict__ xb,
          const float* __restrict__ Wa, ushort* __restrict__ WaT,
          const float* __restrict__ Wo, ushort* __restrict__ WoT)
{
  __shared__ float tile[32][33];
  const int bid = blockIdx.x, t = threadIdx.x;
  if (bid < 3072) {
    int i = (bid * 256 + t) * 8;
    float4 v0 = *(const float4*)(x + i);
    float4 v1 = *(const float4*)(x + i + 4);
    bf16x8 wv;
    wv[0] = (short)f2bf(v0.x); wv[1] = (short)f2bf(v0.y);
    wv[2] = (short)f2bf(v0.z); wv[3] = (short)f2bf(v0.w);
    wv[4] = (short)f2bf(v1.x); wv[5] = (short)f2bf(v1.y);
    wv[6] = (short)f2bf(v1.z); wv[7] = (short)f2bf(v1.w);
    *(bf16x8*)(xb + i) = wv;
    return;
  }
  const int b2 = bid - 3072;
  const int bx = b2 % 96, by = b2 / 96;
  const int tx = t & 31, ty = t >> 5;         // (32,8)
  const float* src; ushort* dst; int C, c0;
  if (bx < 72) { src = Wa; dst = WaT; C = 3 * CEMB; c0 = bx * 32; }
  else         { src = Wo; dst = WoT; C = CEMB;     c0 = (bx - 72) * 32; }
  const int r0 = by * 32;
#pragma unroll
  for (int j = 0; j < 4; ++j)
    tile[ty + j * 8][tx] = src[(size_t)(r0 + ty + j * 8) * C + c0 + tx];
  __syncthreads();
#pragma unroll
  for (int j = 0; j < 4; ++j)
    dst[(size_t)(c0 + ty + j * 8) * CEMB + r0 + tx] = f2bf(tile[tx][ty + j * 8]);
}

// ---------- QKV GEMM (R22-proven: 256x96, 512 threads, zero-tail grid) ----------
__global__ __launch_bounds__(512)
void gemm_qkv(const ushort* __restrict__ A, const ushort* __restrict__ BT,
              const float* __restrict__ bias,
              ushort* __restrict__ qd, ushort* __restrict__ kd, ushort* __restrict__ vd,
              int M, int N, int K)
{
  __shared__ __align__(16) char smem[45056];   // buf p: As @ p*22528 (16KB), Bs @ +16384 (6KB)
  const int t = threadIdx.x;
  const int lane = t & 63, wv = t >> 6;        // 8 waves
  const int cc = lane & 15, gg = lane >> 4;
  const int L = blockIdx.x;
  const int xcd = L & 7, li = L >> 3;          // li in [0, 96)
  const int mi = xcd * 4 + (li & 3);           // 4 M-panels (256 rows) per XCD
  const int ni = li >> 2;                      // 24 N-panels (96 cols)
  const int m0 = mi * 256, n0 = ni * 96;
  const int wm = (wv >> 1) * 64, wn = (wv & 1) * 48;

  const int o0 = t * 16;
  const int o1 = 8192 + t * 16;
  const int r0s = o0 >> 6, s0s = (o0 >> 4) & 3;
  const int r1s = o1 >> 6, s1s = (o1 >> 4) & 3;
  const size_t Kb = (size_t)K * 2;
  const char* a0p = (const char*)A  + (size_t)(m0 + r0s) * Kb + ((s0s ^ ((r0s >> 1) & 3)) << 4);
  const char* a1p = (const char*)A  + (size_t)(m0 + r1s) * Kb + ((s1s ^ ((r1s >> 1) & 3)) << 4);
  const char* b0p = (const char*)BT + (size_t)(n0 + r0s) * Kb + ((s0s ^ ((r0s >> 1) & 3)) << 4);

  auto stage_g = [&](int p, int kb) {
    char* As = smem + p * 22528;
    char* Bs = As + 16384;
    __builtin_amdgcn_global_load_lds(
        (const __attribute__((address_space(1))) unsigned*)(a0p + kb),
        (__attribute__((address_space(3))) unsigned*)(As + wv * 1024), 16, 0, 0);
    __builtin_amdgcn_global_load_lds(
        (const __attribute__((address_space(1))) unsigned*)(a1p + kb),
        (__attribute__((address_space(3))) unsigned*)(As + 8192 + wv * 1024), 16, 0, 0);
    if (wv < 6)   // wave-uniform: waves 0-5 cover B's 6144 bytes
      __builtin_amdgcn_global_load_lds(
          (const __attribute__((address_space(1))) unsigned*)(b0p + kb),
          (__attribute__((address_space(3))) unsigned*)(Bs + wv * 1024), 16, 0, 0);
  };

  f32x4 acc[4][3];
#pragma unroll
  for (int i = 0; i < 4; ++i)
#pragma unroll
    for (int j = 0; j < 3; ++j) acc[i][j] = (f32x4){0.f, 0.f, 0.f, 0.f};

  const int KB = K * 2;
  stage_g(0, 0);
  asm volatile("s_waitcnt vmcnt(0)" ::: "memory");
  __syncthreads();
  int p = 0;
  for (int kb = 0; kb < KB; kb += 64) {
    if (kb + 64 < KB) stage_g(p ^ 1, kb + 64);   // prefetch next tile (overlaps compute)
    const char* As = smem + p * 22528;
    const char* Bs = As + 16384;
    bf16x8 fa[4], fb[3];
#pragma unroll
    for (int i = 0; i < 4; ++i) {
      const int r = wm + i * 16 + cc;             // [0,256)
      fa[i] = *(const bf16x8*)(As + r * 64 + ((gg ^ ((r >> 1) & 3)) << 4));
    }
#pragma unroll
    for (int j = 0; j < 3; ++j) {
      const int r = wn + j * 16 + cc;             // [0,96)
      fb[j] = *(const bf16x8*)(Bs + r * 64 + ((gg ^ ((r >> 1) & 3)) << 4));
    }
    __builtin_amdgcn_s_setprio(1);
#pragma unroll
    for (int i = 0; i < 4; ++i)
#pragma unroll
      for (int j = 0; j < 3; ++j)
        acc[i][j] = __builtin_amdgcn_mfma_f32_16x16x32_bf16(fa[i], fb[j], acc[i][j], 0, 0, 0);
    __builtin_amdgcn_s_setprio(0);
    asm volatile("s_waitcnt vmcnt(0)" ::: "memory");   // next tile's stage landed
    __syncthreads();                                   // all waves done reading buf p
    p ^= 1;
  }

#pragma unroll
  for (int i = 0; i < 4; ++i) {
#pragma unroll
    for (int j = 0; j < 3; ++j) {
      int gm0 = m0 + wm + i * 16 + gg * 4;
      int gn  = n0 + wn + j * 16 + cc;
      float bv = bias[gn];
      int which = gn / CEMB;
      int r = gn - which * CEMB;
      int hh = r >> 6, dd = r & 63;
      int tt0 = gm0 & (TSEQ - 1), bb = gm0 >> 11;   // 4-aligned: same bb for e=0..3
      if (which == 2) {
        ushort* dstv = vd + ((size_t)((bb * NHEAD + hh) * DHEAD + dd)) * TSEQ + tt0;
        uint2 pw;
        pw.x = cvt_pk_bf16(acc[i][j][0] + bv, acc[i][j][1] + bv);
        pw.y = cvt_pk_bf16(acc[i][j][2] + bv, acc[i][j][3] + bv);
        *(uint2*)dstv = pw;
      } else {
        ushort* dst = which == 0 ? qd : kd;
        float sc = (which == 0) ? 0.125f * 1.4426950408889634f : 1.0f;
#pragma unroll
        for (int e = 0; e < 4; ++e)
          dst[(size_t)((bb * NHEAD + hh) * TSEQ + tt0 + e) * DHEAD + dd] =
              f2bf((acc[i][j][e] + bv) * sc);
      }
    }
  }
}

// ---------- output-proj GEMM (R18-proven: 128^2, depth-2 counted-vmcnt, XCD grid) ----------
__global__ __launch_bounds__(256)
void gemm_out(const ushort* __restrict__ A, const ushort* __restrict__ BT,
              const float* __restrict__ bias, float* __restrict__ outF,
              int M, int N, int K)
{
  __shared__ __align__(16) char smem[49152];   // 3 bufs x (As 8KB + Bs 8KB)
  const int t = threadIdx.x;
  const int lane = t & 63, wv = t >> 6;
  const int cc = lane & 15, gg = lane >> 4;
  const int nN = N >> 7, nM = M >> 7;
  const int L = blockIdx.x;
  const int xcd = L & 7, li = L >> 3;
  const int mi = li / nN + (nM >> 3) * xcd;
  const int ni = li % nN;
  const int m0 = mi * 128, n0 = ni * 128;
  const int wm = (wv >> 1) * 64, wn = (wv & 1) * 64;

  const int o0 = wv * 1024 + lane * 16;
  const int o1 = o0 + 4096;
  const int r0s = o0 >> 6, s0s = (o0 >> 4) & 3;
  const int r1s = o1 >> 6, s1s = (o1 >> 4) & 3;
  const size_t Kb = (size_t)K * 2;
  const char* a0p = (const char*)A  + (size_t)(m0 + r0s) * Kb + ((s0s ^ ((r0s >> 1) & 3)) << 4);
  const char* a1p = (const char*)A  + (size_t)(m0 + r1s) * Kb + ((s1s ^ ((r1s >> 1) & 3)) << 4);
  const char* b0p = (const char*)BT + (size_t)(n0 + r0s) * Kb + ((s0s ^ ((r0s >> 1) & 3)) << 4);
  const char* b1p = (const char*)BT + (size_t)(n0 + r1s) * Kb + ((s1s ^ ((r1s >> 1) & 3)) << 4);

  auto stage_g = [&](int p, int kb) {
    char* As = smem + p * 16384;
    char* Bs = As + 8192;
    __builtin_amdgcn_global_load_lds(
        (const __attribute__((address_space(1))) unsigned*)(a0p + kb),
        (__attribute__((address_space(3))) unsigned*)(As + wv * 1024), 16, 0, 0);
    __builtin_amdgcn_global_load_lds(
        (const __attribute__((address_space(1))) unsigned*)(a1p + kb),
        (__attribute__((address_space(3))) unsigned*)(As + wv * 1024 + 4096), 16, 0, 0);
    __builtin_amdgcn_global_load_lds(
        (const __attribute__((address_space(1))) unsigned*)(b0p + kb),
        (__attribute__((address_space(3))) unsigned*)(Bs + wv * 1024), 16, 0, 0);
    __builtin_amdgcn_global_load_lds(
        (const __attribute__((address_space(1))) unsigned*)(b1p + kb),
        (__attribute__((address_space(3))) unsigned*)(Bs + wv * 1024 + 4096), 16, 0, 0);
  };

  f32x4 acc[4][4];
#pragma unroll
  for (int i = 0; i < 4; ++i)
#pragma unroll
    for (int j = 0; j < 4; ++j) acc[i][j] = (f32x4){0.f, 0.f, 0.f, 0.f};

  const int NK = (K * 2) / 64;
  stage_g(0, 0);
  stage_g(1, 64);
  asm volatile("s_waitcnt vmcnt(4)" ::: "memory");
  __builtin_amdgcn_s_barrier();
  __builtin_amdgcn_sched_barrier(0);

  for (int ik = 0; ik < NK; ++ik) {
    const bool pre = (ik + 2 < NK);
    if (pre) stage_g((ik + 2) % 3, (ik + 2) * 64);
    const char* As = smem + (ik % 3) * 16384;
    const char* Bs = As + 8192;
    bf16x8 fa[4], fb[4];
#pragma unroll
    for (int i = 0; i < 4; ++i) {
      const int r = wm + i * 16 + cc;
      fa[i] = *(const bf16x8*)(As + r * 64 + ((gg ^ ((r >> 1) & 3)) << 4));
    }
#pragma unroll
    for (int j = 0; j < 4; ++j) {
      const int r = wn + j * 16 + cc;
      fb[j] = *(const bf16x8*)(Bs + r * 64 + ((gg ^ ((r >> 1) & 3)) << 4));
    }
    __builtin_amdgcn_s_setprio(1);
#pragma unroll
    for (int i = 0; i < 4; ++i)
#pragma unroll
      for (int j = 0; j < 4; ++j)
        acc[i][j] = __builtin_amdgcn_mfma_f32_16x16x32_bf16(fa[i], fb[j], acc[i][j], 0, 0, 0);
    __builtin_amdgcn_s_setprio(0);
    if (ik + 1 < NK) {
      if (pre) asm volatile("s_waitcnt vmcnt(4)" ::: "memory");
      else     asm volatile("s_waitcnt vmcnt(0)" ::: "memory");
      __builtin_amdgcn_s_barrier();
      __builtin_amdgcn_sched_barrier(0);
    }
  }

#pragma unroll
  for (int i = 0; i < 4; ++i) {
#pragma unroll
    for (int j = 0; j < 4; ++j) {
      int gm0 = m0 + wm + i * 16 + gg * 4;
      int gn  = n0 + wn + j * 16 + cc;
      float bv = bias[gn];
#pragma unroll
      for (int e = 0; e < 4; ++e)
        outF[(size_t)(gm0 + e) * N + gn] = acc[i][j][e] + bv;
    }
  }
}

// ---------- flash attention (V single-buffered: LDS 24KB -> 6 blocks/CU) ----------
// R22 post-mortem: attn latency-bound, no pipe >65%; occupancy is the lever (R16).
// V(kt) is written in iter kt and read in iter kt+1, so ONE V buffer suffices with a
// post-PV __syncthreads ordering write-after-read (read-after-write is ordered by the
// existing end-of-iter vmcnt(0)+barrier). LDS 32768 -> 24576 = 6 blocks/CU (+20% TLP)
// for one extra barrier/tile. Everything else R17-proven: 1536-block heavy-first grid,
// K dbuf, register-P via permlane chains, eager-exp softmax, MFMA l-sum, PV overlap.
__global__ __launch_bounds__(256, 6)
void attn_fwd(const ushort* __restrict__ qg, const ushort* __restrict__ kg,
              const ushort* __restrict__ vTg, ushort* __restrict__ ybb)
{
  // LDS: K[2] @ 0 (2 x 8KB, swizzled), V @ 16384 (8KB, swizzled, single-buffered)
  __shared__ __align__(16) char smem[24576];
  const int t = threadIdx.x, lane = t & 63, w = t >> 6;
  const int cc = lane & 15, gg = lane >> 4;
  const int L = blockIdx.x;
  const int slot = L & 7, j = L >> 3;          // j in [0,192)
  const int qt = 31 - j / 6;                   // heavy-first (LPT)
  const int bh = slot + 8 * (j % 6);           // same bh -> same XCD slot
  const int b = bh / NHEAD, h = bh - b * NHEAD;

  const char* Kg = (const char*)(kg + (size_t)bh * TSEQ * DHEAD);   // [T][64], 128B rows
  const char* Vg = (const char*)(vTg + (size_t)bh * TSEQ * DHEAD);  // [64][T], 4096B rows

  const int srow = lane >> 3;                        // row&7 within 8-row chunk
  const int ssw  = ((lane & 7) * 16) ^ (srow << 4);  // pre-swizzled source colbyte

  // shared lane bases for ALL K and V fragment reads
  const int g16s = (gg * 16) ^ ((cc & 7) << 4);
  const char* lb0 = smem + cc * 128 + g16s;
  const char* lb1 = smem + cc * 128 + (g16s ^ 64);

  bf16x8 ones;
#pragma unroll
  for (int i = 0; i < 8; ++i) ones[i] = (short)0x3F80;   // bf16 1.0

  auto stageK = [&](int pb, int kt) {
#pragma unroll
    for (int i = 0; i < 2; ++i) {
      const int c = w * 2 + i;
      const char* gk = Kg + (size_t)(kt * 64 + c * 8 + srow) * 128 + ssw;
      __builtin_amdgcn_global_load_lds(
          (const __attribute__((address_space(1))) unsigned*)gk,
          (__attribute__((address_space(3))) unsigned*)(smem + pb * 8192 + c * 1024),
          16, 0, 0);
    }
  };
  auto stageV = [&](int kt) {
#pragma unroll
    for (int i = 0; i < 2; ++i) {
      const int c = w * 2 + i;
      const char* gv = Vg + (size_t)(c * 8 + srow) * (TSEQ * 2) + (size_t)kt * 128 + ssw;
      __builtin_amdgcn_global_load_lds(
          (const __attribute__((address_space(1))) unsigned*)gv,
          (__attribute__((address_space(3))) unsigned*)(smem + 16384 + c * 1024),
          16, 0, 0);
    }
  };

  const int qrow0 = qt * 64 + w * 16;

  const ushort* Qp = qg + ((size_t)bh * TSEQ + qrow0) * DHEAD;
  bf16x8 fq0 = *(const bf16x8*)(Qp + cc * DHEAD + 8 * gg);
  bf16x8 fq1 = *(const bf16x8*)(Qp + cc * DHEAD + 32 + 8 * gg);

  f32x4 o[4];    // O^T: o[dt][e] = O^T[d = dt*16 + gg*4 + e, q = cc]
  f32x4 l4 = (f32x4){0.f, 0.f, 0.f, 0.f};   // MFMA-ones row-sum acc (elems replicated)
#pragma unroll
  for (int i = 0; i < 4; ++i) o[i] = (f32x4){0.f, 0.f, 0.f, 0.f};
  float m = 0.f;            // running max, log2 domain (eager-exp)
  u32x4 pbf[2];             // P fragments (prev tile), STANDARD B-frag layout
  pbf[0] = (u32x4){0, 0, 0, 0}; pbf[1] = (u32x4){0, 0, 0, 0};

  stageK(0, 0);
  asm volatile("s_waitcnt vmcnt(0)" ::: "memory");
  __syncthreads();

  auto tile = [&](auto PC, int kt) {
    constexpr int P = decltype(PC)::value;
    if (kt < qt) stageK(P ^ 1, kt + 1);   // K for next iter

    // ---- QK(kt) from K[P] (immediate-offset reads off lb0/lb1) ----
    f32x4 st[4];
#pragma unroll
    for (int ct = 0; ct < 4; ++ct) st[ct] = (f32x4){0.f, 0.f, 0.f, 0.f};
    __builtin_amdgcn_s_setprio(1);
#pragma unroll
    for (int ct = 0; ct < 4; ++ct) {
      bf16x8 fk0 = *(const bf16x8*)(lb0 + P * 8192 + ct * 2048);
      bf16x8 fk1 = *(const bf16x8*)(lb1 + P * 8192 + ct * 2048);
      st[ct] = __builtin_amdgcn_mfma_f32_16x16x32_bf16(fk0, fq0, st[ct], 0, 0, 0);
      st[ct] = __builtin_amdgcn_mfma_f32_16x16x32_bf16(fk1, fq1, st[ct], 0, 0, 0);
    }

    // ---- PV(kt-1) + l-sum(kt-1): P from registers, V (single buffer) ----
    if (kt > 0) {
#pragma unroll
      for (int kc = 0; kc < 2; ++kc) {
        bf16x8 pb = __builtin_bit_cast(bf16x8, pbf[kc]);
        l4 = __builtin_amdgcn_mfma_f32_16x16x32_bf16(ones, pb, l4, 0, 0, 0);
        const char* vb = (kc == 0) ? lb0 : lb1;
#pragma unroll
        for (int dt = 0; dt < 4; ++dt) {
          bf16x8 fv = *(const bf16x8*)(vb + 16384 + dt * 2048);
          o[dt] = __builtin_amdgcn_mfma_f32_16x16x32_bf16(fv, pb, o[dt], 0, 0, 0);
        }
      }
    }
    __builtin_amdgcn_s_setprio(0);

    __syncthreads();   // all waves done reading V(kt-1): safe to overwrite
    stageV(kt);        // V(kt) -> V buffer; lands by end-of-iter vmcnt(0)

    // ---- softmax(kt): eager exp with running m ----
    if (kt == qt) {   // causal mask on the diagonal tile
#pragma unroll
      for (int ct = 0; ct < 4; ++ct)
#pragma unroll
        for (int e = 0; e < 4; ++e)
          if (ct * 16 + gg * 4 + e > w * 16 + cc) st[ct][e] = -1e30f;
    }
    f32x4 pe[4];
#pragma unroll
    for (int ct = 0; ct < 4; ++ct)
#pragma unroll
      for (int e = 0; e < 4; ++e) pe[ct][e] = exp2_raw(st[ct][e] - m);
    // per-lane max only; __all() performs the cross-lane reduction for the check
    float ml = fmaxf(fmaxf(st[0][0], st[0][1]), st[0][2]);
    ml = fmaxf(fmaxf(ml, st[0][3]), fmaxf(st[1][0], st[1][1]));
    ml = fmaxf(fmaxf(ml, st[1][2]), fmaxf(st[1][3], st[2][0]));
    ml = fmaxf(fmaxf(ml, st[2][1]), fmaxf(st[2][2], st[2][3]));
    ml = fmaxf(fmaxf(ml, st[3][0]), fmaxf(st[3][1], st[3][2]));
    ml = fmaxf(ml, st[3][3]);
    if (!__all(ml - m <= 11.54f)) {   // rare fixup: shfl-reduce + rescale (no re-exp)
      ml = fmaxf(ml, __shfl_xor(ml, 16, 64));
      ml = fmaxf(ml, __shfl_xor(ml, 32, 64));
      ml = fmaxf(ml, __shfl_xor(ml, 1, 64));
      ml = fmaxf(ml, __shfl_xor(ml, 2, 64));
      ml = fmaxf(ml, __shfl_xor(ml, 4, 64));
      ml = fmaxf(ml, __shfl_xor(ml, 8, 64));
      float mn = fmaxf(m, ml);
      float al = exp2_raw(m - mn);
#pragma unroll
      for (int dt = 0; dt < 4; ++dt)
#pragma unroll
        for (int e = 0; e < 4; ++e) o[dt][e] *= al;
#pragma unroll
      for (int e = 0; e < 4; ++e) l4[e] *= al;
#pragma unroll
      for (int ct = 0; ct < 4; ++ct)
#pragma unroll
        for (int e = 0; e < 4; ++e) pe[ct][e] *= al;
      m = mn;
    }
    // ---- pack + permlane chains: STANDARD B-frag P(kt) into registers ----
    {
      unsigned X0 = cvt_pk_bf16(pe[0][0], pe[0][1]), X1 = cvt_pk_bf16(pe[0][2], pe[0][3]);
      unsigned Y0 = cvt_pk_bf16(pe[1][0], pe[1][1]), Y1 = cvt_pk_bf16(pe[1][2], pe[1][3]);
      unsigned Z0 = cvt_pk_bf16(pe[2][0], pe[2][1]), Z1 = cvt_pk_bf16(pe[2][2], pe[2][3]);
      unsigned W0 = cvt_pk_bf16(pe[3][0], pe[3][1]), W1 = cvt_pk_bf16(pe[3][2], pe[3][3]);
      permswap32(X0, Y0); permswap16(X0, Y0);
      permswap32(X1, Y1); permswap16(X1, Y1);
      permswap32(Z0, W0); permswap16(Z0, W0);
      permswap32(Z1, W1); permswap16(Z1, W1);
      pbf[0] = (u32x4){X0, X1, Y0, Y1};
      pbf[1] = (u32x4){Z0, Z1, W0, W1};
    }

    asm volatile("s_waitcnt vmcnt(0)" ::: "memory");   // K(kt+1) + V(kt) landed
    __syncthreads();                                   // all waves done with buf P
  };

  for (int kt = 0; kt <= qt; kt += 2) {
    tile(IC<0>{}, kt);
    if (kt + 1 <= qt) tile(IC<1>{}, kt + 1);
  }

  // ---- epilogue: PV(qt) + l-sum(qt) from the single V buffer (holds V(qt)) ----
  {
#pragma unroll
    for (int kc = 0; kc < 2; ++kc) {
      bf16x8 pb = __builtin_bit_cast(bf16x8, pbf[kc]);
      l4 = __builtin_amdgcn_mfma_f32_16x16x32_bf16(ones, pb, l4, 0, 0, 0);
      const char* vb = (kc == 0) ? lb0 : lb1;
#pragma unroll
      for (int dt = 0; dt < 4; ++dt) {
        bf16x8 fv = *(const bf16x8*)(vb + 16384 + dt * 2048);
        o[dt] = __builtin_amdgcn_mfma_f32_16x16x32_bf16(fv, pb, o[dt], 0, 0, 0);
      }
    }
  }

  float inv = 1.0f / l4[0];
  ushort* yrow = ybb + (size_t)(b * TSEQ + qrow0 + cc) * CEMB + h * DHEAD;
#pragma unroll
  for (int dt = 0; dt < 4; ++dt) {
    uint2 pw;
    pw.x = cvt_pk_bf16(o[dt][0] * inv, o[dt][1] * inv);
    pw.y = cvt_pk_bf16(o[dt][2] * inv, o[dt][3] * inv);
    *(uint2*)(yrow + dt * 16 + gg * 4) = pw;
  }
}

extern "C" void kernel_launch(void* const* d_in, const int* in_sizes, int n_in,
                              void* d_out, int out_size, void* d_ws, size_t ws_size,
                              hipStream_t stream)
{
  (void)in_sizes; (void)n_in; (void)out_size; (void)ws_size;
  const float* x  = (const float*)d_in[0];
  const float* Wa = (const float*)d_in[1];
  const float* ba = (const float*)d_in[2];
  const float* Wo = (const float*)d_in[3];
  const float* bo = (const float*)d_in[4];
  float* out = (float*)d_out;

  char* p = (char*)d_ws;
  ushort* WaT  = (ushort*)p; p += (size_t)3 * CEMB * CEMB * 2;               // [2304][768] bf16
  ushort* WoT  = (ushort*)p; p += (size_t)CEMB * CEMB * 2;                   // [768][768] bf16
  ushort* xb   = (ushort*)p; p += (size_t)NBATCH * TSEQ * CEMB * 2;          // x bf16 [B*T][C]
  ushort* qb   = (ushort*)p; p += (size_t)NBATCH * NHEAD * TSEQ * DHEAD * 2; // [B,H,T,D]
  ushort* kb   = (ushort*)p; p += (size_t)NBATCH * NHEAD * TSEQ * DHEAD * 2;
  ushort* vT   = (ushort*)p; p += (size_t)NBATCH * NHEAD * TSEQ * DHEAD * 2; // [B,H,D,T] (direct)
  ushort* yb   = (ushort*)p; p += (size_t)NBATCH * TSEQ * CEMB * 2;          // attn out bf16

  prep<<<3072 + 96 * 24, 256, 0, stream>>>(x, xb, Wa, WaT, Wo, WoT);
  gemm_qkv<<<dim3((NBATCH * TSEQ / 256) * (3 * CEMB / 96)), 512, 0, stream>>>(
      xb, WaT, ba, qb, kb, vT, NBATCH * TSEQ, 3 * CEMB, CEMB);
  attn_fwd<<<dim3(1536), 256, 0, stream>>>(qb, kb, vT, yb);
  gemm_out<<<dim3((NBATCH * TSEQ / 128) * (CEMB / 128)), 256, 0, stream>>>(
      yb, WoT, bo, out, NBATCH * TSEQ, CEMB, CEMB);
}

// Round 24
// 113.528 us; speedup vs baseline: 1.1584x; 1.1584x over previous
//
#include <hip/hip_runtime.h>
#include <hip/hip_bf16.h>

#define NHEAD 12
#define TSEQ 2048
#define CEMB 768
#define DHEAD 64
#define NBATCH 4

typedef __attribute__((ext_vector_type(8))) short bf16x8;
typedef __attribute__((ext_vector_type(4))) float f32x4;
typedef __attribute__((ext_vector_type(4))) unsigned u32x4;

template <int N> struct IC { static constexpr int value = N; };

__device__ __forceinline__ ushort f2bf(float f) {
  union { float f; unsigned u; } v; v.f = f;
  unsigned u = v.u;
  u += 0x7FFFu + ((u >> 16) & 1u);   // RNE to bf16
  return (ushort)(u >> 16);
}

// packed f32x2 -> bf16x2 (1 inst, RNE) — T12 primitive
__device__ __forceinline__ unsigned cvt_pk_bf16(float lo, float hi) {
  unsigned r;
  asm("v_cvt_pk_bf16_f32 %0, %1, %2" : "=v"(r) : "v"(lo), "v"(hi));
  return r;
}

// raw v_exp_f32: D = 2^S0 (scores pre-scaled to log2 domain)
__device__ __forceinline__ float exp2_raw(float x) {
  float r;
  asm("v_exp_f32 %0, %1" : "=v"(r) : "v"(x));
  return r;
}

// v_permlane32_swap_b32 (semantics validated R14):
// new_a = [a.lanes0-31 | b.lanes0-31], new_b = [a.lanes32-63 | b.lanes32-63]
__device__ __forceinline__ void permswap32(unsigned& a, unsigned& b) {
  asm("v_permlane32_swap_b32 %0, %1" : "+v"(a), "+v"(b));
}
// v_permlane16_swap_b32 (validated R15): swap a's odd 16-rows with b's even 16-rows
__device__ __forceinline__ void permswap16(unsigned& a, unsigned& b) {
  asm("v_permlane16_swap_b32 %0, %1" : "+v"(a), "+v"(b));
}

// ---------- fused prep: cast x -> bf16, transpose+cast Wa and Wo ----------
__global__ __launch_bounds__(256)
void prep(const float* __restrict__ x, ushort* __restrict__ xb,
          const float* __restrict__ Wa, ushort* __restrict__ WaT,
          const float* __restrict__ Wo, ushort* __restrict__ WoT)
{
  __shared__ float tile[32][33];
  const int bid = blockIdx.x, t = threadIdx.x;
  if (bid < 3072) {
    int i = (bid * 256 + t) * 8;
    float4 v0 = *(const float4*)(x + i);
    float4 v1 = *(const float4*)(x + i + 4);
    bf16x8 wv;
    wv[0] = (short)f2bf(v0.x); wv[1] = (short)f2bf(v0.y);
    wv[2] = (short)f2bf(v0.z); wv[3] = (short)f2bf(v0.w);
    wv[4] = (short)f2bf(v1.x); wv[5] = (short)f2bf(v1.y);
    wv[6] = (short)f2bf(v1.z); wv[7] = (short)f2bf(v1.w);
    *(bf16x8*)(xb + i) = wv;
    return;
  }
  const int b2 = bid - 3072;
  const int bx = b2 % 96, by = b2 / 96;
  const int tx = t & 31, ty = t >> 5;         // (32,8)
  const float* src; ushort* dst; int C, c0;
  if (bx < 72) { src = Wa; dst = WaT; C = 3 * CEMB; c0 = bx * 32; }
  else         { src = Wo; dst = WoT; C = CEMB;     c0 = (bx - 72) * 32; }
  const int r0 = by * 32;
#pragma unroll
  for (int j = 0; j < 4; ++j)
    tile[ty + j * 8][tx] = src[(size_t)(r0 + ty + j * 8) * C + c0 + tx];
  __syncthreads();
#pragma unroll
  for (int j = 0; j < 4; ++j)
    dst[(size_t)(c0 + ty + j * 8) * CEMB + r0 + tx] = f2bf(tile[tx][ty + j * 8]);
}

// ---------- QKV GEMM (R22-proven: 256x96, 512 threads, zero-tail grid) ----------
__global__ __launch_bounds__(512)
void gemm_qkv(const ushort* __restrict__ A, const ushort* __restrict__ BT,
              const float* __restrict__ bias,
              ushort* __restrict__ qd, ushort* __restrict__ kd, ushort* __restrict__ vd,
              int M, int N, int K)
{
  __shared__ __align__(16) char smem[45056];   // buf p: As @ p*22528 (16KB), Bs @ +16384 (6KB)
  const int t = threadIdx.x;
  const int lane = t & 63, wv = t >> 6;        // 8 waves
  const int cc = lane & 15, gg = lane >> 4;
  const int L = blockIdx.x;
  const int xcd = L & 7, li = L >> 3;          // li in [0, 96)
  const int mi = xcd * 4 + (li & 3);           // 4 M-panels (256 rows) per XCD
  const int ni = li >> 2;                      // 24 N-panels (96 cols)
  const int m0 = mi * 256, n0 = ni * 96;
  const int wm = (wv >> 1) * 64, wn = (wv & 1) * 48;

  const int o0 = t * 16;
  const int o1 = 8192 + t * 16;
  const int r0s = o0 >> 6, s0s = (o0 >> 4) & 3;
  const int r1s = o1 >> 6, s1s = (o1 >> 4) & 3;
  const size_t Kb = (size_t)K * 2;
  const char* a0p = (const char*)A  + (size_t)(m0 + r0s) * Kb + ((s0s ^ ((r0s >> 1) & 3)) << 4);
  const char* a1p = (const char*)A  + (size_t)(m0 + r1s) * Kb + ((s1s ^ ((r1s >> 1) & 3)) << 4);
  const char* b0p = (const char*)BT + (size_t)(n0 + r0s) * Kb + ((s0s ^ ((r0s >> 1) & 3)) << 4);

  auto stage_g = [&](int p, int kb) {
    char* As = smem + p * 22528;
    char* Bs = As + 16384;
    __builtin_amdgcn_global_load_lds(
        (const __attribute__((address_space(1))) unsigned*)(a0p + kb),
        (__attribute__((address_space(3))) unsigned*)(As + wv * 1024), 16, 0, 0);
    __builtin_amdgcn_global_load_lds(
        (const __attribute__((address_space(1))) unsigned*)(a1p + kb),
        (__attribute__((address_space(3))) unsigned*)(As + 8192 + wv * 1024), 16, 0, 0);
    if (wv < 6)   // wave-uniform: waves 0-5 cover B's 6144 bytes
      __builtin_amdgcn_global_load_lds(
          (const __attribute__((address_space(1))) unsigned*)(b0p + kb),
          (__attribute__((address_space(3))) unsigned*)(Bs + wv * 1024), 16, 0, 0);
  };

  f32x4 acc[4][3];
#pragma unroll
  for (int i = 0; i < 4; ++i)
#pragma unroll
    for (int j = 0; j < 3; ++j) acc[i][j] = (f32x4){0.f, 0.f, 0.f, 0.f};

  const int KB = K * 2;
  stage_g(0, 0);
  asm volatile("s_waitcnt vmcnt(0)" ::: "memory");
  __syncthreads();
  int p = 0;
  for (int kb = 0; kb < KB; kb += 64) {
    if (kb + 64 < KB) stage_g(p ^ 1, kb + 64);   // prefetch next tile (overlaps compute)
    const char* As = smem + p * 22528;
    const char* Bs = As + 16384;
    bf16x8 fa[4], fb[3];
#pragma unroll
    for (int i = 0; i < 4; ++i) {
      const int r = wm + i * 16 + cc;             // [0,256)
      fa[i] = *(const bf16x8*)(As + r * 64 + ((gg ^ ((r >> 1) & 3)) << 4));
    }
#pragma unroll
    for (int j = 0; j < 3; ++j) {
      const int r = wn + j * 16 + cc;             // [0,96)
      fb[j] = *(const bf16x8*)(Bs + r * 64 + ((gg ^ ((r >> 1) & 3)) << 4));
    }
    __builtin_amdgcn_s_setprio(1);
#pragma unroll
    for (int i = 0; i < 4; ++i)
#pragma unroll
      for (int j = 0; j < 3; ++j)
        acc[i][j] = __builtin_amdgcn_mfma_f32_16x16x32_bf16(fa[i], fb[j], acc[i][j], 0, 0, 0);
    __builtin_amdgcn_s_setprio(0);
    asm volatile("s_waitcnt vmcnt(0)" ::: "memory");   // next tile's stage landed
    __syncthreads();                                   // all waves done reading buf p
    p ^= 1;
  }

#pragma unroll
  for (int i = 0; i < 4; ++i) {
#pragma unroll
    for (int j = 0; j < 3; ++j) {
      int gm0 = m0 + wm + i * 16 + gg * 4;
      int gn  = n0 + wn + j * 16 + cc;
      float bv = bias[gn];
      int which = gn / CEMB;
      int r = gn - which * CEMB;
      int hh = r >> 6, dd = r & 63;
      int tt0 = gm0 & (TSEQ - 1), bb = gm0 >> 11;   // 4-aligned: same bb for e=0..3
      if (which == 2) {
        ushort* dstv = vd + ((size_t)((bb * NHEAD + hh) * DHEAD + dd)) * TSEQ + tt0;
        uint2 pw;
        pw.x = cvt_pk_bf16(acc[i][j][0] + bv, acc[i][j][1] + bv);
        pw.y = cvt_pk_bf16(acc[i][j][2] + bv, acc[i][j][3] + bv);
        *(uint2*)dstv = pw;
      } else {
        ushort* dst = which == 0 ? qd : kd;
        float sc = (which == 0) ? 0.125f * 1.4426950408889634f : 1.0f;
#pragma unroll
        for (int e = 0; e < 4; ++e)
          dst[(size_t)((bb * NHEAD + hh) * TSEQ + tt0 + e) * DHEAD + dd] =
              f2bf((acc[i][j][e] + bv) * sc);
      }
    }
  }
}

// ---------- output-proj GEMM (R18-proven: 128^2, depth-2 counted-vmcnt, XCD grid) ----------
__global__ __launch_bounds__(256)
void gemm_out(const ushort* __restrict__ A, const ushort* __restrict__ BT,
              const float* __restrict__ bias, float* __restrict__ outF,
              int M, int N, int K)
{
  __shared__ __align__(16) char smem[49152];   // 3 bufs x (As 8KB + Bs 8KB)
  const int t = threadIdx.x;
  const int lane = t & 63, wv = t >> 6;
  const int cc = lane & 15, gg = lane >> 4;
  const int nN = N >> 7, nM = M >> 7;
  const int L = blockIdx.x;
  const int xcd = L & 7, li = L >> 3;
  const int mi = li / nN + (nM >> 3) * xcd;
  const int ni = li % nN;
  const int m0 = mi * 128, n0 = ni * 128;
  const int wm = (wv >> 1) * 64, wn = (wv & 1) * 64;

  const int o0 = wv * 1024 + lane * 16;
  const int o1 = o0 + 4096;
  const int r0s = o0 >> 6, s0s = (o0 >> 4) & 3;
  const int r1s = o1 >> 6, s1s = (o1 >> 4) & 3;
  const size_t Kb = (size_t)K * 2;
  const char* a0p = (const char*)A  + (size_t)(m0 + r0s) * Kb + ((s0s ^ ((r0s >> 1) & 3)) << 4);
  const char* a1p = (const char*)A  + (size_t)(m0 + r1s) * Kb + ((s1s ^ ((r1s >> 1) & 3)) << 4);
  const char* b0p = (const char*)BT + (size_t)(n0 + r0s) * Kb + ((s0s ^ ((r0s >> 1) & 3)) << 4);
  const char* b1p = (const char*)BT + (size_t)(n0 + r1s) * Kb + ((s1s ^ ((r1s >> 1) & 3)) << 4);

  auto stage_g = [&](int p, int kb) {
    char* As = smem + p * 16384;
    char* Bs = As + 8192;
    __builtin_amdgcn_global_load_lds(
        (const __attribute__((address_space(1))) unsigned*)(a0p + kb),
        (__attribute__((address_space(3))) unsigned*)(As + wv * 1024), 16, 0, 0);
    __builtin_amdgcn_global_load_lds(
        (const __attribute__((address_space(1))) unsigned*)(a1p + kb),
        (__attribute__((address_space(3))) unsigned*)(As + wv * 1024 + 4096), 16, 0, 0);
    __builtin_amdgcn_global_load_lds(
        (const __attribute__((address_space(1))) unsigned*)(b0p + kb),
        (__attribute__((address_space(3))) unsigned*)(Bs + wv * 1024), 16, 0, 0);
    __builtin_amdgcn_global_load_lds(
        (const __attribute__((address_space(1))) unsigned*)(b1p + kb),
        (__attribute__((address_space(3))) unsigned*)(Bs + wv * 1024 + 4096), 16, 0, 0);
  };

  f32x4 acc[4][4];
#pragma unroll
  for (int i = 0; i < 4; ++i)
#pragma unroll
    for (int j = 0; j < 4; ++j) acc[i][j] = (f32x4){0.f, 0.f, 0.f, 0.f};

  const int NK = (K * 2) / 64;
  stage_g(0, 0);
  stage_g(1, 64);
  asm volatile("s_waitcnt vmcnt(4)" ::: "memory");
  __builtin_amdgcn_s_barrier();
  __builtin_amdgcn_sched_barrier(0);

  for (int ik = 0; ik < NK; ++ik) {
    const bool pre = (ik + 2 < NK);
    if (pre) stage_g((ik + 2) % 3, (ik + 2) * 64);
    const char* As = smem + (ik % 3) * 16384;
    const char* Bs = As + 8192;
    bf16x8 fa[4], fb[4];
#pragma unroll
    for (int i = 0; i < 4; ++i) {
      const int r = wm + i * 16 + cc;
      fa[i] = *(const bf16x8*)(As + r * 64 + ((gg ^ ((r >> 1) & 3)) << 4));
    }
#pragma unroll
    for (int j = 0; j < 4; ++j) {
      const int r = wn + j * 16 + cc;
      fb[j] = *(const bf16x8*)(Bs + r * 64 + ((gg ^ ((r >> 1) & 3)) << 4));
    }
    __builtin_amdgcn_s_setprio(1);
#pragma unroll
    for (int i = 0; i < 4; ++i)
#pragma unroll
      for (int j = 0; j < 4; ++j)
        acc[i][j] = __builtin_amdgcn_mfma_f32_16x16x32_bf16(fa[i], fb[j], acc[i][j], 0, 0, 0);
    __builtin_amdgcn_s_setprio(0);
    if (ik + 1 < NK) {
      if (pre) asm volatile("s_waitcnt vmcnt(4)" ::: "memory");
      else     asm volatile("s_waitcnt vmcnt(0)" ::: "memory");
      __builtin_amdgcn_s_barrier();
      __builtin_amdgcn_sched_barrier(0);
    }
  }

#pragma unroll
  for (int i = 0; i < 4; ++i) {
#pragma unroll
    for (int j = 0; j < 4; ++j) {
      int gm0 = m0 + wm + i * 16 + gg * 4;
      int gn  = n0 + wn + j * 16 + cc;
      float bv = bias[gn];
#pragma unroll
      for (int e = 0; e < 4; ++e)
        outF[(size_t)(gm0 + e) * N + gn] = acc[i][j][e] + bv;
    }
  }
}

// ---------- flash attention (R17-proven: VGPR-freed, unrolled x2, immediate-offset LDS)
__global__ __launch_bounds__(256, 5)
void attn_fwd(const ushort* __restrict__ qg, const ushort* __restrict__ kg,
              const ushort* __restrict__ vTg, ushort* __restrict__ ybb)
{
  // LDS: K[2] @ 0 (2 x 8KB, swizzled), V[2] @ 16384 (2 x 8KB, swizzled)
  __shared__ __align__(16) char smem[32768];
  const int t = threadIdx.x, lane = t & 63, w = t >> 6;
  const int cc = lane & 15, gg = lane >> 4;
  const int L = blockIdx.x;
  const int slot = L & 7, j = L >> 3;          // j in [0,192)
  const int qt = 31 - j / 6;                   // heavy-first (LPT)
  const int bh = slot + 8 * (j % 6);           // same bh -> same XCD slot
  const int b = bh / NHEAD, h = bh - b * NHEAD;

  const char* Kg = (const char*)(kg + (size_t)bh * TSEQ * DHEAD);   // [T][64], 128B rows
  const char* Vg = (const char*)(vTg + (size_t)bh * TSEQ * DHEAD);  // [64][T], 4096B rows

  const int srow = lane >> 3;                        // row&7 within 8-row chunk
  const int ssw  = ((lane & 7) * 16) ^ (srow << 4);  // pre-swizzled source colbyte

  // shared lane bases for ALL K and V fragment reads
  const int g16s = (gg * 16) ^ ((cc & 7) << 4);
  const char* lb0 = smem + cc * 128 + g16s;
  const char* lb1 = smem + cc * 128 + (g16s ^ 64);

  bf16x8 ones;
#pragma unroll
  for (int i = 0; i < 8; ++i) ones[i] = (short)0x3F80;   // bf16 1.0

  auto stageK = [&](int pb, int kt) {
#pragma unroll
    for (int i = 0; i < 2; ++i) {
      const int c = w * 2 + i;
      const char* gk = Kg + (size_t)(kt * 64 + c * 8 + srow) * 128 + ssw;
      __builtin_amdgcn_global_load_lds(
          (const __attribute__((address_space(1))) unsigned*)gk,
          (__attribute__((address_space(3))) unsigned*)(smem + pb * 8192 + c * 1024),
          16, 0, 0);
    }
  };
  auto stageV = [&](int pb, int kt) {
#pragma unroll
    for (int i = 0; i < 2; ++i) {
      const int c = w * 2 + i;
      const char* gv = Vg + (size_t)(c * 8 + srow) * (TSEQ * 2) + (size_t)kt * 128 + ssw;
      __builtin_amdgcn_global_load_lds(
          (const __attribute__((address_space(1))) unsigned*)gv,
          (__attribute__((address_space(3))) unsigned*)(smem + 16384 + pb * 8192 + c * 1024),
          16, 0, 0);
    }
  };

  const int qrow0 = qt * 64 + w * 16;

  const ushort* Qp = qg + ((size_t)bh * TSEQ + qrow0) * DHEAD;
  bf16x8 fq0 = *(const bf16x8*)(Qp + cc * DHEAD + 8 * gg);
  bf16x8 fq1 = *(const bf16x8*)(Qp + cc * DHEAD + 32 + 8 * gg);

  f32x4 o[4];    // O^T: o[dt][e] = O^T[d = dt*16 + gg*4 + e, q = cc]
  f32x4 l4 = (f32x4){0.f, 0.f, 0.f, 0.f};   // MFMA-ones row-sum acc (elems replicated)
#pragma unroll
  for (int i = 0; i < 4; ++i) o[i] = (f32x4){0.f, 0.f, 0.f, 0.f};
  float m = 0.f;            // running max, log2 domain (eager-exp)
  u32x4 pbf[2];             // P fragments (prev tile), STANDARD B-frag layout
  pbf[0] = (u32x4){0, 0, 0, 0}; pbf[1] = (u32x4){0, 0, 0, 0};

  stageK(0, 0);
  asm volatile("s_waitcnt vmcnt(0)" ::: "memory");
  __syncthreads();

  auto tile = [&](auto PC, int kt) {
    constexpr int P = decltype(PC)::value;
    if (kt < qt) stageK(P ^ 1, kt + 1);   // K for next iter
    stageV(P, kt);                        // V consumed next iter (PV(kt))

    // ---- QK(kt) from K[P] (immediate-offset reads off lb0/lb1) ----
    f32x4 st[4];
#pragma unroll
    for (int ct = 0; ct < 4; ++ct) st[ct] = (f32x4){0.f, 0.f, 0.f, 0.f};
    __builtin_amdgcn_s_setprio(1);
#pragma unroll
    for (int ct = 0; ct < 4; ++ct) {
      bf16x8 fk0 = *(const bf16x8*)(lb0 + P * 8192 + ct * 2048);
      bf16x8 fk1 = *(const bf16x8*)(lb1 + P * 8192 + ct * 2048);
      st[ct] = __builtin_amdgcn_mfma_f32_16x16x32_bf16(fk0, fq0, st[ct], 0, 0, 0);
      st[ct] = __builtin_amdgcn_mfma_f32_16x16x32_bf16(fk1, fq1, st[ct], 0, 0, 0);
    }

    // ---- PV(kt-1) + l-sum(kt-1): P from registers, V[P^1] ----
    if (kt > 0) {
#pragma unroll
      for (int kc = 0; kc < 2; ++kc) {
        bf16x8 pb = __builtin_bit_cast(bf16x8, pbf[kc]);
        l4 = __builtin_amdgcn_mfma_f32_16x16x32_bf16(ones, pb, l4, 0, 0, 0);
        const char* vb = (kc == 0) ? lb0 : lb1;
#pragma unroll
        for (int dt = 0; dt < 4; ++dt) {
          bf16x8 fv = *(const bf16x8*)(vb + 16384 + (P ^ 1) * 8192 + dt * 2048);
          o[dt] = __builtin_amdgcn_mfma_f32_16x16x32_bf16(fv, pb, o[dt], 0, 0, 0);
        }
      }
    }
    __builtin_amdgcn_s_setprio(0);

    // ---- softmax(kt): eager exp with running m ----
    if (kt == qt) {   // causal mask on the diagonal tile
#pragma unroll
      for (int ct = 0; ct < 4; ++ct)
#pragma unroll
        for (int e = 0; e < 4; ++e)
          if (ct * 16 + gg * 4 + e > w * 16 + cc) st[ct][e] = -1e30f;
    }
    f32x4 pe[4];
#pragma unroll
    for (int ct = 0; ct < 4; ++ct)
#pragma unroll
      for (int e = 0; e < 4; ++e) pe[ct][e] = exp2_raw(st[ct][e] - m);
    // per-lane max only; __all() performs the cross-lane reduction for the check
    float ml = fmaxf(fmaxf(st[0][0], st[0][1]), st[0][2]);
    ml = fmaxf(fmaxf(ml, st[0][3]), fmaxf(st[1][0], st[1][1]));
    ml = fmaxf(fmaxf(ml, st[1][2]), fmaxf(st[1][3], st[2][0]));
    ml = fmaxf(fmaxf(ml, st[2][1]), fmaxf(st[2][2], st[2][3]));
    ml = fmaxf(fmaxf(ml, st[3][0]), fmaxf(st[3][1], st[3][2]));
    ml = fmaxf(ml, st[3][3]);
    if (!__all(ml - m <= 11.54f)) {   // rare fixup: shfl-reduce + rescale (no re-exp)
      ml = fmaxf(ml, __shfl_xor(ml, 16, 64));
      ml = fmaxf(ml, __shfl_xor(ml, 32, 64));
      ml = fmaxf(ml, __shfl_xor(ml, 1, 64));
      ml = fmaxf(ml, __shfl_xor(ml, 2, 64));
      ml = fmaxf(ml, __shfl_xor(ml, 4, 64));
      ml = fmaxf(ml, __shfl_xor(ml, 8, 64));
      float mn = fmaxf(m, ml);
      float al = exp2_raw(m - mn);
#pragma unroll
      for (int dt = 0; dt < 4; ++dt)
#pragma unroll
        for (int e = 0; e < 4; ++e) o[dt][e] *= al;
#pragma unroll
      for (int e = 0; e < 4; ++e) l4[e] *= al;
#pragma unroll
      for (int ct = 0; ct < 4; ++ct)
#pragma unroll
        for (int e = 0; e < 4; ++e) pe[ct][e] *= al;
      m = mn;
    }
    // ---- pack + permlane chains: STANDARD B-frag P(kt) into registers ----
    {
      unsigned X0 = cvt_pk_bf16(pe[0][0], pe[0][1]), X1 = cvt_pk_bf16(pe[0][2], pe[0][3]);
      unsigned Y0 = cvt_pk_bf16(pe[1][0], pe[1][1]), Y1 = cvt_pk_bf16(pe[1][2], pe[1][3]);
      unsigned Z0 = cvt_pk_bf16(pe[2][0], pe[2][1]), Z1 = cvt_pk_bf16(pe[2][2], pe[2][3]);
      unsigned W0 = cvt_pk_bf16(pe[3][0], pe[3][1]), W1 = cvt_pk_bf16(pe[3][2], pe[3][3]);
      permswap32(X0, Y0); permswap16(X0, Y0);
      permswap32(X1, Y1); permswap16(X1, Y1);
      permswap32(Z0, W0); permswap16(Z0, W0);
      permswap32(Z1, W1); permswap16(Z1, W1);
      pbf[0] = (u32x4){X0, X1, Y0, Y1};
      pbf[1] = (u32x4){Z0, Z1, W0, W1};
    }

    asm volatile("s_waitcnt vmcnt(0)" ::: "memory");   // K(kt+1) + V(kt) landed
    __syncthreads();                                   // all waves done with buf P
  };

  for (int kt = 0; kt <= qt; kt += 2) {
    tile(IC<0>{}, kt);
    if (kt + 1 <= qt) tile(IC<1>{}, kt + 1);
  }

  // ---- epilogue: PV(qt) + l-sum(qt) from V[qt&1] ----
  {
    const int pl = qt & 1;
#pragma unroll
    for (int kc = 0; kc < 2; ++kc) {
      bf16x8 pb = __builtin_bit_cast(bf16x8, pbf[kc]);
      l4 = __builtin_amdgcn_mfma_f32_16x16x32_bf16(ones, pb, l4, 0, 0, 0);
      const char* vb = (kc == 0) ? lb0 : lb1;
#pragma unroll
      for (int dt = 0; dt < 4; ++dt) {
        bf16x8 fv = *(const bf16x8*)(vb + 16384 + pl * 8192 + dt * 2048);
        o[dt] = __builtin_amdgcn_mfma_f32_16x16x32_bf16(fv, pb, o[dt], 0, 0, 0);
      }
    }
  }

  float inv = 1.0f / l4[0];
  ushort* yrow = ybb + (size_t)(b * TSEQ + qrow0 + cc) * CEMB + h * DHEAD;
#pragma unroll
  for (int dt = 0; dt < 4; ++dt) {
    uint2 pw;
    pw.x = cvt_pk_bf16(o[dt][0] * inv, o[dt][1] * inv);
    pw.y = cvt_pk_bf16(o[dt][2] * inv, o[dt][3] * inv);
    *(uint2*)(yrow + dt * 16 + gg * 4) = pw;
  }
}

extern "C" void kernel_launch(void* const* d_in, const int* in_sizes, int n_in,
                              void* d_out, int out_size, void* d_ws, size_t ws_size,
                              hipStream_t stream)
{
  (void)in_sizes; (void)n_in; (void)out_size; (void)ws_size;
  const float* x  = (const float*)d_in[0];
  const float* Wa = (const float*)d_in[1];
  const float* ba = (const float*)d_in[2];
  const float* Wo = (const float*)d_in[3];
  const float* bo = (const float*)d_in[4];
  float* out = (float*)d_out;

  char* p = (char*)d_ws;
  ushort* WaT  = (ushort*)p; p += (size_t)3 * CEMB * CEMB * 2;               // [2304][768] bf16
  ushort* WoT  = (ushort*)p; p += (size_t)CEMB * CEMB * 2;                   // [768][768] bf16
  ushort* xb   = (ushort*)p; p += (size_t)NBATCH * TSEQ * CEMB * 2;          // x bf16 [B*T][C]
  ushort* qb   = (ushort*)p; p += (size_t)NBATCH * NHEAD * TSEQ * DHEAD * 2; // [B,H,T,D]
  ushort* kb   = (ushort*)p; p += (size_t)NBATCH * NHEAD * TSEQ * DHEAD * 2;
  ushort* vT   = (ushort*)p; p += (size_t)NBATCH * NHEAD * TSEQ * DHEAD * 2; // [B,H,D,T] (direct)
  ushort* yb   = (ushort*)p; p += (size_t)NBATCH * TSEQ * CEMB * 2;          // attn out bf16

  prep<<<3072 + 96 * 24, 256, 0, stream>>>(x, xb, Wa, WaT, Wo, WoT);
  gemm_qkv<<<dim3((NBATCH * TSEQ / 256) * (3 * CEMB / 96)), 512, 0, stream>>>(
      xb, WaT, ba, qb, kb, vT, NBATCH * TSEQ, 3 * CEMB, CEMB);
  attn_fwd<<<dim3(1536), 256, 0, stream>>>(qb, kb, vT, yb);
  gemm_out<<<dim3((NBATCH * TSEQ / 128) * (CEMB / 128)), 256, 0, stream>>>(
      yb, WoT, bo, out, NBATCH * TSEQ, CEMB, CEMB);
}